// Round 10
// baseline (90.267 us; speedup 1.0000x reference)
//
#include <hip/hip_runtime.h>
#include <stdint.h>

// ---------------------------------------------------------------------------
// GraphBasedSkipConnection, MI355X. f32 I/O; bf16 MFMA GEMMs internally.
//   B=2, H=64, W=64, C=512, C2=256, N = 8192 pixels.
// Round 10: revert to round-7 structure (best, 65.7us) with ONE change:
//   mid types 1/2/3 fused into a single edge block computing Tv/TeD/TeR
//   together (shared Weu_bot B-frags, shared staging/barriers; 24 MFMA per
//   8KB of B vs 16 before). Grid 768 = 512 edge + 256 uv = 3 blocks/CU.
// ---------------------------------------------------------------------------

typedef __attribute__((ext_vector_type(8))) short bf16x8;
typedef __attribute__((ext_vector_type(4))) float f32x4;

#define EPS_BN 1e-3f

__device__ __forceinline__ short f2bf(float f) {
    union { float f; unsigned u; } cv;
    cv.f = f;
    unsigned r = cv.u + 0x7fffu + ((cv.u >> 16) & 1u);
    return (short)(r >> 16);
}
__device__ __forceinline__ float bf2f(short s) {
    union { unsigned u; float f; } cv;
    cv.u = ((unsigned)(unsigned short)s) << 16;
    return cv.f;
}

// ---- P layout (floats) -----------------------------------------------------
// 0 a1, 1 c1, 2 a4, 3 c4
// 8..264    a2[256]     264..520  c2[256]
// 520..776  a3[256]     776..1032 c3[256]
// 1032..1544 a5[512]    1544..2056 c5[512]
// 2056..2060 w_ea[4]    2060..2064 w_er[4]
// ---------------------------------------------------------------------------

__device__ __forceinline__ void pack_one(const float* __restrict__ W, short* __restrict__ out,
                                         int K, int Ncol, int lb, int tid) {
    int i = lb * 256 + tid;
    int lane = i & 63, tile = i >> 6;
    int ktiles = K >> 5;
    int nt = tile / ktiles, kt = tile - nt * ktiles;
    int kbase = (kt << 5) + ((lane >> 4) << 3);
    int col = (nt << 4) + (lane & 15);
    bf16x8 v;
    #pragma unroll
    for (int j = 0; j < 8; ++j) v[j] = f2bf(W[(kbase + j) * Ncol + col]);
    ((bf16x8*)out)[(tile << 6) + lane] = v;
}

// blocks 0..2047: stencil (xb, agg); 2048..2175 pack W_vu; 2176..2303 pack
// W_eu; 2304..2495 pack W_fc; 2496 computes P.
__global__ __launch_bounds__(256) void k_front(
    const float* __restrict__ x,
    const float* w_ea, const float* b_ea,
    const float* g1, const float* b1, const float* m1, const float* v1,
    const float* w_vu, const float* w_eu, const float* w_fc,
    const float* b_vu, const float* g2, const float* b2_, const float* m2, const float* v2,
    const float* b_eu, const float* g3, const float* b3, const float* m3, const float* v3,
    const float* w_er, const float* b_er,
    const float* g4, const float* b4, const float* m4, const float* v4,
    const float* g5, const float* b5, const float* m5, const float* v5,
    short* __restrict__ xb, short* __restrict__ agg,
    short* BpVu, short* BpEu, short* BpFc, float* P)
{
    int blk = blockIdx.x, t = threadIdx.x;
    if (blk >= 2048) {
        int b = blk - 2048;
        if (b < 128)      { pack_one(w_vu, BpVu, 1024, 256, b, t); }
        else if (b < 256) { pack_one(w_eu, BpEu, 1024, 256, b - 128, t); }
        else if (b < 448) { pack_one(w_fc, BpFc,  768, 512, b - 256, t); }
        else {
            for (int u = t; u < 512; u += 256) {
                float a5 = g5[u] * rsqrtf(v5[u] + EPS_BN);
                P[1032 + u] = a5;
                P[1544 + u] = b5[u] - m5[u] * a5;      // w_fc has no bias
            }
            {
                float a2 = g2[t] * rsqrtf(v2[t] + EPS_BN);
                P[8 + t]   = a2;
                P[264 + t] = (b_vu[t] - m2[t]) * a2 + b2_[t];
                float a3 = g3[t] * rsqrtf(v3[t] + EPS_BN);
                P[520 + t] = a3;
                P[776 + t] = (b_eu[t] - m3[t]) * a3 + b3[t];
            }
            if (t < 4) {
                P[2056 + t] = w_ea[t];
                P[2060 + t] = w_er[t];
            }
            if (t == 0) {
                float a4 = g4[0] * rsqrtf(v4[0] + EPS_BN);
                P[2] = a4;
                P[3] = (b_er[0] - m4[0]) * a4 + b4[0];
                float a1l = g1[0] * rsqrtf(v1[0] + EPS_BN);
                P[0] = a1l;
                P[1] = (b_ea[0] - m1[0]) * a1l + b1[0];
            }
        }
        return;
    }

    float a1 = g1[0] * rsqrtf(v1[0] + EPS_BN);
    float c1 = (b_ea[0] - m1[0]) * a1 + b1[0];
    float w0 = w_ea[0], w1 = w_ea[1], w2 = w_ea[2], w3 = w_ea[3];

    int idx = blk * 256 + t;                    // N*C/8 threads
    int n = idx >> 6;
    int ci = idx & 63;
    int bh = n >> 6, h = bh & 63, w = n & 63;
    int bhb = bh & ~63;
    int rowU = ((bhb + ((h + 63) & 63)) << 6) + w;
    int rowD = ((bhb + ((h + 1) & 63)) << 6) + w;
    int rowL = (bh << 6) + ((w + 63) & 63);
    int rowR = (bh << 6) + ((w + 1) & 63);

    const f32x4* xv = (const f32x4*)x;
    int c4 = ci << 1;
    f32x4 vc[2], vU[2], vD[2], vL[2], vR[2];
    #pragma unroll
    for (int h2 = 0; h2 < 2; ++h2) {
        vc[h2] = xv[(n    << 7) + c4 + h2];
        vU[h2] = xv[(rowU << 7) + c4 + h2];
        vD[h2] = xv[(rowD << 7) + c4 + h2];
        vL[h2] = xv[(rowL << 7) + c4 + h2];
        vR[h2] = xv[(rowR << 7) + c4 + h2];
    }

    bf16x8 ob, xbv;
    #pragma unroll
    for (int h2 = 0; h2 < 2; ++h2) {
        #pragma unroll
        for (int j = 0; j < 4; ++j) {
            int e = h2 * 4 + j;
            float xc = vc[h2][j];
            float S = w0 * (xc * vU[h2][j]) + w1 * (xc * vD[h2][j])
                    + w2 * (xc * vL[h2][j]) + w3 * (xc * vR[h2][j]);
            ob[e]  = f2bf(fmaxf(fmaf(a1, S, c1), 0.f));
            xbv[e] = f2bf(xc);
        }
    }
    int o = (n << 6) + ci;
    ((bf16x8*)agg)[o] = ob;
    ((bf16x8*)xb)[o] = xbv;
}

// ---------------------------------------------------------------------------
// k_gemm_mid, grid 768:
//   blocks 0..511  : EDGE — Tv/TeD/TeR fused. 32 rows x 128 cols (ch half).
//                    wave 32x32 (nf=2), 3 acc sets, 8 chunks, 24 MFMA/chunk.
//   blocks 512..767: UV   — uv = relu(bn2([xb,agg]@W_vu)). 32r x 256c,
//                    wave 32x64 (nf=4), 16 chunks (round-7 type 0).
// ---------------------------------------------------------------------------

#define E_LOAD(gx, gd, gr, kc) do {                                           \
    gx = *(const bf16x8*)(xb + xoff + ((kc) << 6) + lcs);                     \
    gd = *(const bf16x8*)(xb + doff + ((kc) << 6) + lcs);                     \
    gr = *(const bf16x8*)(xb + roff + ((kc) << 6) + lcs);                     \
} while (0)

#define E_WRITE(slot, gx, gd, gr) do {                                        \
    bf16x8 _vd, _vr;                                                          \
    _Pragma("unroll") for (int _j = 0; _j < 8; ++_j) {                        \
        float _x = bf2f(gx[_j]);                                              \
        _vd[_j] = f2bf(_x * bf2f(gd[_j]));                                    \
        _vr[_j] = f2bf(_x * bf2f(gr[_j]));                                    \
    }                                                                         \
    ((bf16x8*)sX[slot])[t] = gx;                                              \
    ((bf16x8*)sD[slot])[t] = _vd;                                             \
    ((bf16x8*)sR[slot])[t] = _vr;                                             \
} while (0)

#define E_COMPUTE(slot, kc) do {                                              \
    const short* _LX = sX[slot];                                              \
    const short* _LD = sD[slot];                                              \
    const short* _LR = sR[slot];                                              \
    _Pragma("unroll") for (int _kt = 0; _kt < 2; ++_kt) {                     \
        bf16x8 _aX[2], _aD[2], _aR[2];                                        \
        _Pragma("unroll") for (int _mi = 0; _mi < 2; ++_mi) {                 \
            int _row = (_mi << 4) + (l & 15);                                 \
            int _lcolb = (_kt << 6) + ((l >> 4) << 4);                        \
            int _addr = (_row << 6) + ((_lcolb ^ ((_row & 7) << 4)) >> 1);    \
            _aX[_mi] = *(const bf16x8*)(_LX + _addr);                         \
            _aD[_mi] = *(const bf16x8*)(_LD + _addr);                         \
            _aR[_mi] = *(const bf16x8*)(_LR + _addr);                         \
        }                                                                     \
        int _kt32 = ((kc) << 1) + _kt;                                        \
        _Pragma("unroll") for (int _nf = 0; _nf < 2; ++_nf) {                 \
            bf16x8 _bT = Be[((nt0 + _nf) * 32 + _kt32) * 64 + l];             \
            bf16x8 _bB = Be[((nt0 + _nf) * 32 + 16 + _kt32) * 64 + l];        \
            _Pragma("unroll") for (int _mi = 0; _mi < 2; ++_mi) {             \
                aV[_mi][_nf] = __builtin_amdgcn_mfma_f32_16x16x32_bf16(       \
                    _aX[_mi], _bT, aV[_mi][_nf], 0, 0, 0);                    \
                aD_[_mi][_nf] = __builtin_amdgcn_mfma_f32_16x16x32_bf16(      \
                    _aD[_mi], _bB, aD_[_mi][_nf], 0, 0, 0);                   \
                aR_[_mi][_nf] = __builtin_amdgcn_mfma_f32_16x16x32_bf16(      \
                    _aR[_mi], _bB, aR_[_mi][_nf], 0, 0, 0);                   \
            }                                                                 \
        }                                                                     \
    }                                                                         \
} while (0)

#define UV_SRC(kc) (((kc) < 8 ? xb : agg) + xoff + (((kc) & 7) << 6) + lcs)

#define UV_COMPUTE(slot, kc) do {                                             \
    const short* _Lb = sX[slot];                                              \
    _Pragma("unroll") for (int _kt = 0; _kt < 2; ++_kt) {                     \
        bf16x8 _af[2];                                                        \
        _Pragma("unroll") for (int _mi = 0; _mi < 2; ++_mi) {                 \
            int _row = (_mi << 4) + (l & 15);                                 \
            int _lcolb = (_kt << 6) + ((l >> 4) << 4);                        \
            int _addr = (_row << 6) + ((_lcolb ^ ((_row & 7) << 4)) >> 1);    \
            _af[_mi] = *(const bf16x8*)(_Lb + _addr);                         \
        }                                                                     \
        int _kt32 = ((kc) << 1) + _kt;                                        \
        _Pragma("unroll") for (int _nf = 0; _nf < 4; ++_nf) {                 \
            bf16x8 _b = Bv[((((w << 2) + _nf) << 5) + _kt32) * 64 + l];       \
            _Pragma("unroll") for (int _mi = 0; _mi < 2; ++_mi)               \
                acc[_mi][_nf] = __builtin_amdgcn_mfma_f32_16x16x32_bf16(      \
                    _af[_mi], _b, acc[_mi][_nf], 0, 0, 0);                    \
        }                                                                     \
    }                                                                         \
} while (0)

__global__ __launch_bounds__(256) void k_gemm_mid(
    const short* __restrict__ xb, const short* __restrict__ agg,
    const short* __restrict__ BpVu, const short* __restrict__ BpEu,
    const float* __restrict__ P,
    short* __restrict__ uvb, short* __restrict__ tvb,
    short* __restrict__ teDb, short* __restrict__ teRb)
{
    __shared__ __align__(16) short sX[2][32 * 64];    // 8 KB
    __shared__ __align__(16) short sD[2][32 * 64];    // 8 KB
    __shared__ __align__(16) short sR[2][32 * 64];    // 8 KB
    int t = threadIdx.x, l = t & 63, w = t >> 6;
    int bid = blockIdx.x;
    int dr = t >> 3, p8 = t & 7;
    int lcs = (p8 ^ (dr & 7)) << 3;

    if (bid < 512) {
        // -------- EDGE: Tv / TeD / TeR fused --------
        int rs = bid >> 1, ch = bid & 1;
        int r0 = rs << 5;
        int rA = r0 + dr;
        int bh = rA >> 6;
        int nD = (((bh & ~63) + (((bh & 63) + 1) & 63)) << 6) + (rA & 63);
        int nR = (rA & ~63) + ((rA + 1) & 63);
        int xoff = rA << 9, doff = nD << 9, roff = nR << 9;
        int nt0 = (ch << 3) + (w << 1);
        const bf16x8* Be = (const bf16x8*)BpEu;

        f32x4 aV[2][2], aD_[2][2], aR_[2][2];
        #pragma unroll
        for (int mi = 0; mi < 2; ++mi)
            #pragma unroll
            for (int nf = 0; nf < 2; ++nf) {
                aV[mi][nf]  = (f32x4){0.f, 0.f, 0.f, 0.f};
                aD_[mi][nf] = (f32x4){0.f, 0.f, 0.f, 0.f};
                aR_[mi][nf] = (f32x4){0.f, 0.f, 0.f, 0.f};
            }

        bf16x8 gX0, gD0, gR0, gX1, gD1, gR1;
        E_LOAD(gX0, gD0, gR0, 0);
        E_LOAD(gX1, gD1, gR1, 1);
        for (int kc2 = 0; kc2 < 8; kc2 += 2) {
            E_WRITE(0, gX0, gD0, gR0);
            __syncthreads();
            if (kc2 + 2 < 8) E_LOAD(gX0, gD0, gR0, kc2 + 2);
            E_COMPUTE(0, kc2);
            E_WRITE(1, gX1, gD1, gR1);
            __syncthreads();
            if (kc2 + 3 < 8) E_LOAD(gX1, gD1, gR1, kc2 + 3);
            E_COMPUTE(1, kc2 + 1);
        }

        #pragma unroll
        for (int nf = 0; nf < 2; ++nf) {
            int col = (ch << 7) + (w << 5) + (nf << 4) + (l & 15);
            #pragma unroll
            for (int mi = 0; mi < 2; ++mi) {
                int rbase = r0 + (mi << 4) + ((l >> 4) << 2);
                #pragma unroll
                for (int j = 0; j < 4; ++j) {
                    tvb [(rbase + j) * 256 + col] = f2bf(aV[mi][nf][j]);
                    teDb[(rbase + j) * 256 + col] = f2bf(aD_[mi][nf][j]);
                    teRb[(rbase + j) * 256 + col] = f2bf(aR_[mi][nf][j]);
                }
            }
        }
    } else {
        // -------- UV: relu(bn2([xb,agg] @ W_vu)) --------
        int rs = bid - 512;
        int r0 = rs << 5;
        int xoff = (r0 + dr) << 9;
        const bf16x8* Bv = (const bf16x8*)BpVu;

        f32x4 acc[2][4];
        #pragma unroll
        for (int mi = 0; mi < 2; ++mi)
            #pragma unroll
            for (int nf = 0; nf < 4; ++nf) acc[mi][nf] = (f32x4){0.f, 0.f, 0.f, 0.f};

        bf16x8 gA = *(const bf16x8*)UV_SRC(0);
        bf16x8 gB = *(const bf16x8*)UV_SRC(1);
        for (int kc2 = 0; kc2 < 16; kc2 += 2) {
            ((bf16x8*)sX[0])[t] = gA;
            __syncthreads();
            if (kc2 + 2 < 16) gA = *(const bf16x8*)UV_SRC(kc2 + 2);
            UV_COMPUTE(0, kc2);
            ((bf16x8*)sX[1])[t] = gB;
            __syncthreads();
            if (kc2 + 3 < 16) gB = *(const bf16x8*)UV_SRC(kc2 + 3);
            UV_COMPUTE(1, kc2 + 1);
        }

        #pragma unroll
        for (int nf = 0; nf < 4; ++nf) {
            int col = (w << 6) + (nf << 4) + (l & 15);
            float aa = P[8 + col], cc = P[264 + col];
            #pragma unroll
            for (int mi = 0; mi < 2; ++mi) {
                int rbase = r0 + (mi << 4) + ((l >> 4) << 2);
                #pragma unroll
                for (int j = 0; j < 4; ++j) {
                    float v = fmaxf(fmaf(acc[mi][nf][j], aa, cc), 0.f);
                    uvb[(rbase + j) * 256 + col] = f2bf(v);
                }
            }
        }
    }
}

// out = relu(bn5([xb, upd] @ W_fc)), upd computed in-kernel into LDS.
// block: 32 rows x 128 cols (quarter cq), 4 waves (wave 32x32), grid 1024.
#define OUT_COMPUTE(Lb, kc) do {                                              \
    _Pragma("unroll") for (int _kt = 0; _kt < 2; ++_kt) {                     \
        bf16x8 _af[2];                                                        \
        _Pragma("unroll") for (int _mi = 0; _mi < 2; ++_mi) {                 \
            int _row = (_mi << 4) + (l & 15);                                 \
            int _lcolb = (_kt << 6) + ((l >> 4) << 4);                        \
            int _addr = (_row << 6) + ((_lcolb ^ ((_row & 7) << 4)) >> 1);    \
            _af[_mi] = *(const bf16x8*)((Lb) + _addr);                        \
        }                                                                     \
        _Pragma("unroll") for (int _nf = 0; _nf < 2; ++_nf) {                 \
            int _nt = (cq << 3) + (w << 1) + _nf;                             \
            bf16x8 _b = Bp[(_nt * 24 + ((kc) << 1) + _kt) * 64 + l];          \
            _Pragma("unroll") for (int _mi = 0; _mi < 2; ++_mi)               \
                acc[_mi][_nf] = __builtin_amdgcn_mfma_f32_16x16x32_bf16(      \
                    _af[_mi], _b, acc[_mi][_nf], 0, 0, 0);                    \
        }                                                                     \
    }                                                                         \
} while (0)

__global__ __launch_bounds__(256) void k_gemm_out(
    const short* __restrict__ xb,
    const short* __restrict__ tv, const short* __restrict__ teD,
    const short* __restrict__ teR, const short* __restrict__ uv,
    const short* __restrict__ BpFc, const float* __restrict__ P,
    float* __restrict__ out)
{
    __shared__ __align__(16) short sXb[2][32 * 64];   // 8 KB
    __shared__ __align__(16) short updL[4][32 * 64];  // 16 KB
    int t = threadIdx.x, l = t & 63, w = t >> 6;
    int cq = blockIdx.x & 3, rs = blockIdx.x >> 2;
    int r0 = rs << 5;
    const bf16x8* Bp = (const bf16x8*)BpFc;

    int dr = t >> 3, p8 = t & 7;
    int lcs = (p8 ^ (dr & 7)) << 3;
    int xrow = (r0 + dr) << 9;

    // prefetch first two xb chunks before the upd prologue
    bf16x8 gA = *(const bf16x8*)(xb + xrow + lcs);
    bf16x8 gB = *(const bf16x8*)(xb + xrow + 64 + lcs);

    // ---- prologue: upd for rows r0..r0+31, all 256 channels, into LDS ----
    {
        int n = r0 + dr;
        int bh = n >> 6, h = bh & 63, ww = n & 63;
        int bhb = bh & ~63;
        int nUp = ((bhb + ((h + 63) & 63)) << 6) + ww;
        int nLf = (bh << 6) + ((ww + 63) & 63);
        float w0 = P[2060], w1 = P[2061], w2 = P[2062], w3 = P[2063];
        float a4 = P[2], c4 = P[3];
        #pragma unroll
        for (int q = 0; q < 4; ++q) {
            int lc = (q << 6) + lcs;
            bf16x8 vTv = *(const bf16x8*)(tv  + n   * 256 + lc);
            bf16x8 vD  = *(const bf16x8*)(teD + n   * 256 + lc);
            bf16x8 vDu = *(const bf16x8*)(teD + nUp * 256 + lc);
            bf16x8 vR  = *(const bf16x8*)(teR + n   * 256 + lc);
            bf16x8 vRl = *(const bf16x8*)(teR + nLf * 256 + lc);
            bf16x8 vUv = *(const bf16x8*)(uv  + n   * 256 + lc);
            f32x4 a3a = *(const f32x4*)&P[520 + lc], a3b = *(const f32x4*)&P[524 + lc];
            f32x4 c3a = *(const f32x4*)&P[776 + lc], c3b = *(const f32x4*)&P[780 + lc];
            bf16x8 o;
            #pragma unroll
            for (int j = 0; j < 8; ++j) {
                float a3 = (j < 4) ? a3a[j & 3] : a3b[j & 3];
                float c3 = (j < 4) ? c3a[j & 3] : c3b[j & 3];
                float tvv = bf2f(vTv[j]);
                float ueU = fmaxf(fmaf(a3, tvv + bf2f(vDu[j]), c3), 0.f);
                float ueD = fmaxf(fmaf(a3, tvv + bf2f(vD[j]),  c3), 0.f);
                float ueL = fmaxf(fmaf(a3, tvv + bf2f(vRl[j]), c3), 0.f);
                float ueR = fmaxf(fmaf(a3, tvv + bf2f(vR[j]),  c3), 0.f);
                float s = w0 * ueU + w1 * ueD + w2 * ueL + w3 * ueR;
                float ur = fmaxf(fmaf(a4, s, c4), 0.f);
                o[j] = f2bf(ur * bf2f(vUv[j]));
            }
            *(bf16x8*)&updL[q][(dr << 6) + (p8 << 3)] = o;   // swizzled store
        }
    }

    f32x4 acc[2][2];
    #pragma unroll
    for (int mi = 0; mi < 2; ++mi)
        #pragma unroll
        for (int nf = 0; nf < 2; ++nf) acc[mi][nf] = (f32x4){0.f, 0.f, 0.f, 0.f};

    for (int kc2 = 0; kc2 < 8; kc2 += 2) {
        ((bf16x8*)sXb[0])[t] = gA;
        __syncthreads();
        if (kc2 + 2 < 8) gA = *(const bf16x8*)(xb + xrow + ((kc2 + 2) << 6) + lcs);
        OUT_COMPUTE(sXb[0], kc2);
        ((bf16x8*)sXb[1])[t] = gB;
        __syncthreads();
        if (kc2 + 3 < 8) gB = *(const bf16x8*)(xb + xrow + ((kc2 + 3) << 6) + lcs);
        OUT_COMPUTE(sXb[1], kc2 + 1);
    }
    #pragma unroll
    for (int ku = 0; ku < 4; ++ku) OUT_COMPUTE(updL[ku], 8 + ku);

    #pragma unroll
    for (int nf = 0; nf < 2; ++nf) {
        int col = (cq << 7) + (w << 5) + (nf << 4) + (l & 15);
        float a5 = P[1032 + col], c5 = P[1544 + col];
        #pragma unroll
        for (int mi = 0; mi < 2; ++mi) {
            int rbase = r0 + (mi << 4) + ((l >> 4) << 2);
            #pragma unroll
            for (int j = 0; j < 4; ++j) {
                out[(rbase + j) * 512 + col] = fmaxf(fmaf(acc[mi][nf][j], a5, c5), 0.f);
            }
        }
    }
}

extern "C" void kernel_launch(void* const* d_in, const int* in_sizes, int n_in,
                              void* d_out, int out_size, void* d_ws, size_t ws_size,
                              hipStream_t stream)
{
    const float* x    = (const float*)d_in[0];
    const float* w_ea = (const float*)d_in[1];
    const float* b_ea = (const float*)d_in[2];
    const float* g1   = (const float*)d_in[3];
    const float* b1   = (const float*)d_in[4];
    const float* m1   = (const float*)d_in[5];
    const float* v1   = (const float*)d_in[6];
    const float* w_vu = (const float*)d_in[7];
    const float* b_vu = (const float*)d_in[8];
    const float* g2   = (const float*)d_in[9];
    const float* b2   = (const float*)d_in[10];
    const float* m2   = (const float*)d_in[11];
    const float* v2   = (const float*)d_in[12];
    const float* w_eu = (const float*)d_in[13];
    const float* b_eu = (const float*)d_in[14];
    const float* g3   = (const float*)d_in[15];
    const float* b3   = (const float*)d_in[16];
    const float* m3   = (const float*)d_in[17];
    const float* v3   = (const float*)d_in[18];
    const float* w_er = (const float*)d_in[19];
    const float* b_er = (const float*)d_in[20];
    const float* g4   = (const float*)d_in[21];
    const float* b4   = (const float*)d_in[22];
    const float* m4   = (const float*)d_in[23];
    const float* v4   = (const float*)d_in[24];
    const float* w_fc = (const float*)d_in[25];
    const float* g5   = (const float*)d_in[26];
    const float* b5   = (const float*)d_in[27];
    const float* m5   = (const float*)d_in[28];
    const float* v5   = (const float*)d_in[29];

    char* ws = (char*)d_ws;
    float* P = (float*)ws;
    size_t off = 16384;
    short* BpVu = (short*)(ws + off); off += (size_t)1024 * 256 * 2;
    short* BpEu = (short*)(ws + off); off += (size_t)1024 * 256 * 2;
    short* BpFc = (short*)(ws + off); off += (size_t)768 * 512 * 2;
    short* xbb  = (short*)(ws + off); off += (size_t)8192 * 512 * 2;
    short* aggb = (short*)(ws + off); off += (size_t)8192 * 512 * 2;
    short* uvb  = (short*)(ws + off); off += (size_t)8192 * 256 * 2;
    short* tvb  = (short*)(ws + off); off += (size_t)8192 * 256 * 2;
    short* teDb = (short*)(ws + off); off += (size_t)8192 * 256 * 2;
    short* teRb = (short*)(ws + off); off += (size_t)8192 * 256 * 2;

    k_front<<<2497, 256, 0, stream>>>(x, w_ea, b_ea, g1, b1, m1, v1,
                                      w_vu, w_eu, w_fc,
                                      b_vu, g2, b2, m2, v2,
                                      b_eu, g3, b3, m3, v3,
                                      w_er, b_er, g4, b4, m4, v4,
                                      g5, b5, m5, v5,
                                      xbb, aggb, BpVu, BpEu, BpFc, P);
    k_gemm_mid<<<768, 256, 0, stream>>>(xbb, aggb, BpVu, BpEu, P,
                                        uvb, tvb, teDb, teRb);
    k_gemm_out<<<1024, 256, 0, stream>>>(xbb, tvb, teDb, teRb, uvb, BpFc, P,
                                         (float*)d_out);
}

// Round 11
// 76.038 us; speedup vs baseline: 1.1871x; 1.1871x over previous
//
#include <hip/hip_runtime.h>
#include <stdint.h>

// ---------------------------------------------------------------------------
// GraphBasedSkipConnection, MI355X. f32 I/O; bf16 MFMA GEMMs internally.
//   B=2, H=64, W=64, C=512, C2=256, N = 8192 pixels.
// Round 11: B-STATIONARY mid GEMM. Diagnosis (r10 profile): every A-staged
// variant is latency-bound (MfmaUtil ~7%, VALU ~8%, HBM ~6%) because A
// crosses a barrier every ~16 MFMAs. Fix: stage the small reused B-panel in
// LDS once per block (64c x Khalf = 64KB), stream A fragments straight from
// global (row-major xb IS fragment order) -> zero barriers in compute loops.
//   mid grid 512: blocks 0..255 edge (Tv then TeD+TeR, shared bot-B),
//                 blocks 256..511 uv. 1 edge + 1 uv per CU.
//   prodD/prodR materialized in k_front so mid has no VALU pack at all.
// k_front(+prod) / k_gemm_out unchanged from round 7 (best, 65.7us).
// ---------------------------------------------------------------------------

typedef __attribute__((ext_vector_type(8))) short bf16x8;
typedef __attribute__((ext_vector_type(4))) float f32x4;

#define EPS_BN 1e-3f

__device__ __forceinline__ short f2bf(float f) {
    union { float f; unsigned u; } cv;
    cv.f = f;
    unsigned r = cv.u + 0x7fffu + ((cv.u >> 16) & 1u);
    return (short)(r >> 16);
}
__device__ __forceinline__ float bf2f(short s) {
    union { unsigned u; float f; } cv;
    cv.u = ((unsigned)(unsigned short)s) << 16;
    return cv.f;
}

// ---- P layout (floats) -----------------------------------------------------
// 0 a1, 1 c1, 2 a4, 3 c4
// 8..264    a2[256]     264..520  c2[256]
// 520..776  a3[256]     776..1032 c3[256]
// 1032..1544 a5[512]    1544..2056 c5[512]
// 2056..2060 w_ea[4]    2060..2064 w_er[4]
// ---------------------------------------------------------------------------

__device__ __forceinline__ void pack_one(const float* __restrict__ W, short* __restrict__ out,
                                         int K, int Ncol, int lb, int tid) {
    int i = lb * 256 + tid;
    int lane = i & 63, tile = i >> 6;
    int ktiles = K >> 5;
    int nt = tile / ktiles, kt = tile - nt * ktiles;
    int kbase = (kt << 5) + ((lane >> 4) << 3);
    int col = (nt << 4) + (lane & 15);
    bf16x8 v;
    #pragma unroll
    for (int j = 0; j < 8; ++j) v[j] = f2bf(W[(kbase + j) * Ncol + col]);
    ((bf16x8*)out)[(tile << 6) + lane] = v;
}

// blocks 0..2047: stencil (xb, agg, prodD, prodR); 2048..2175 pack W_vu;
// 2176..2303 pack W_eu; 2304..2495 pack W_fc; 2496 computes P.
__global__ __launch_bounds__(256) void k_front(
    const float* __restrict__ x,
    const float* w_ea, const float* b_ea,
    const float* g1, const float* b1, const float* m1, const float* v1,
    const float* w_vu, const float* w_eu, const float* w_fc,
    const float* b_vu, const float* g2, const float* b2_, const float* m2, const float* v2,
    const float* b_eu, const float* g3, const float* b3, const float* m3, const float* v3,
    const float* w_er, const float* b_er,
    const float* g4, const float* b4, const float* m4, const float* v4,
    const float* g5, const float* b5, const float* m5, const float* v5,
    short* __restrict__ xb, short* __restrict__ agg,
    short* __restrict__ prodD, short* __restrict__ prodR,
    short* BpVu, short* BpEu, short* BpFc, float* P)
{
    int blk = blockIdx.x, t = threadIdx.x;
    if (blk >= 2048) {
        int b = blk - 2048;
        if (b < 128)      { pack_one(w_vu, BpVu, 1024, 256, b, t); }
        else if (b < 256) { pack_one(w_eu, BpEu, 1024, 256, b - 128, t); }
        else if (b < 448) { pack_one(w_fc, BpFc,  768, 512, b - 256, t); }
        else {
            for (int u = t; u < 512; u += 256) {
                float a5 = g5[u] * rsqrtf(v5[u] + EPS_BN);
                P[1032 + u] = a5;
                P[1544 + u] = b5[u] - m5[u] * a5;      // w_fc has no bias
            }
            {
                float a2 = g2[t] * rsqrtf(v2[t] + EPS_BN);
                P[8 + t]   = a2;
                P[264 + t] = (b_vu[t] - m2[t]) * a2 + b2_[t];
                float a3 = g3[t] * rsqrtf(v3[t] + EPS_BN);
                P[520 + t] = a3;
                P[776 + t] = (b_eu[t] - m3[t]) * a3 + b3[t];
            }
            if (t < 4) {
                P[2056 + t] = w_ea[t];
                P[2060 + t] = w_er[t];
            }
            if (t == 0) {
                float a4 = g4[0] * rsqrtf(v4[0] + EPS_BN);
                P[2] = a4;
                P[3] = (b_er[0] - m4[0]) * a4 + b4[0];
                float a1l = g1[0] * rsqrtf(v1[0] + EPS_BN);
                P[0] = a1l;
                P[1] = (b_ea[0] - m1[0]) * a1l + b1[0];
            }
        }
        return;
    }

    float a1 = g1[0] * rsqrtf(v1[0] + EPS_BN);
    float c1 = (b_ea[0] - m1[0]) * a1 + b1[0];
    float w0 = w_ea[0], w1 = w_ea[1], w2 = w_ea[2], w3 = w_ea[3];

    int idx = blk * 256 + t;                    // N*C/8 threads
    int n = idx >> 6;
    int ci = idx & 63;
    int bh = n >> 6, h = bh & 63, w = n & 63;
    int bhb = bh & ~63;
    int rowU = ((bhb + ((h + 63) & 63)) << 6) + w;
    int rowD = ((bhb + ((h + 1) & 63)) << 6) + w;
    int rowL = (bh << 6) + ((w + 63) & 63);
    int rowR = (bh << 6) + ((w + 1) & 63);

    const f32x4* xv = (const f32x4*)x;
    int c4 = ci << 1;
    f32x4 vc[2], vU[2], vD[2], vL[2], vR[2];
    #pragma unroll
    for (int h2 = 0; h2 < 2; ++h2) {
        vc[h2] = xv[(n    << 7) + c4 + h2];
        vU[h2] = xv[(rowU << 7) + c4 + h2];
        vD[h2] = xv[(rowD << 7) + c4 + h2];
        vL[h2] = xv[(rowL << 7) + c4 + h2];
        vR[h2] = xv[(rowR << 7) + c4 + h2];
    }

    bf16x8 ob, xbv, pD, pR;
    #pragma unroll
    for (int h2 = 0; h2 < 2; ++h2) {
        #pragma unroll
        for (int j = 0; j < 4; ++j) {
            int e = h2 * 4 + j;
            float xc = vc[h2][j];
            float eU = xc * vU[h2][j], eD = xc * vD[h2][j];
            float eL = xc * vL[h2][j], eR = xc * vR[h2][j];
            float S = w0 * eU + w1 * eD + w2 * eL + w3 * eR;
            ob[e]  = f2bf(fmaxf(fmaf(a1, S, c1), 0.f));
            xbv[e] = f2bf(xc);
            pD[e] = f2bf(eD);
            pR[e] = f2bf(eR);
        }
    }
    int o = (n << 6) + ci;
    ((bf16x8*)agg)[o] = ob;
    ((bf16x8*)xb)[o] = xbv;
    ((bf16x8*)prodD)[o] = pD;
    ((bf16x8*)prodR)[o] = pR;
}

// ---------------------------------------------------------------------------
// k_gemm_mid (B-stationary), grid 512:
//   blocks 0..255  : EDGE  (cs = b&3 colslice of 64, rg = b>>2 of 64 x 128 rows)
//                    phase1: stage BpEu[cs4..+4][kt 0..16] (64KB) -> Tv = xb@top
//                    phase2: stage BpEu[..][kt 16..32]     -> TeD,TeR = prod@bot
//   blocks 256..511: UV    phase1: BpVu k<512, A=xb ; phase2: BpVu k>=512, A=agg
// Block 256 thr = 4 waves; wave owns 32 rows (mi=2), all 64 cols (ntl=4).
// Compute loops have NO barriers: A streams global->reg->MFMA, B from LDS.
// ---------------------------------------------------------------------------

#define MFMA16(a, b, c) __builtin_amdgcn_mfma_f32_16x16x32_bf16(a, b, c, 0, 0, 0)

// copy 4 nt x 16 kt x 1KB fragment slab into sB
#define STAGE_B(Bsrc, ktoff) do {                                             \
    const bf16x8* _g = (const bf16x8*)(Bsrc);                                 \
    bf16x8* _s = (bf16x8*)sB;                                                 \
    _Pragma("unroll") for (int _i = 0; _i < 16; ++_i) {                       \
        int _u = (_i << 8) + t;                                               \
        int _ntl = _u >> 10;                                                  \
        _s[_u] = _g[((cs4 + _ntl) << 11) + ((ktoff) << 6) + (_u & 1023)];     \
    }                                                                         \
} while (0)

// one-source sweep: acc[2][4] += S-rows x B   (16 kt, no barriers)
#define SWEEP1(S, acc) do {                                                   \
    _Pragma("unroll") for (int _kt = 0; _kt < 16; ++_kt) {                    \
        bf16x8 _a0 = *(const bf16x8*)((S) + ((arow0      ) << 9) + (_kt << 5) + kseg); \
        bf16x8 _a1 = *(const bf16x8*)((S) + ((arow0 + 16 ) << 9) + (_kt << 5) + kseg); \
        _Pragma("unroll") for (int _n = 0; _n < 4; ++_n) {                    \
            bf16x8 _b = ((const bf16x8*)sB)[(_n << 10) + (_kt << 6) + l];     \
            acc[0][_n] = MFMA16(_a0, _b, acc[0][_n]);                         \
            acc[1][_n] = MFMA16(_a1, _b, acc[1][_n]);                         \
        }                                                                     \
    }                                                                         \
} while (0)

// two-source sweep sharing B: accD += S1 x B ; accR += S2 x B
#define SWEEP2(S1, accD, S2, accR) do {                                       \
    _Pragma("unroll") for (int _kt = 0; _kt < 16; ++_kt) {                    \
        bf16x8 _d0 = *(const bf16x8*)((S1) + ((arow0      ) << 9) + (_kt << 5) + kseg); \
        bf16x8 _d1 = *(const bf16x8*)((S1) + ((arow0 + 16 ) << 9) + (_kt << 5) + kseg); \
        bf16x8 _r0 = *(const bf16x8*)((S2) + ((arow0      ) << 9) + (_kt << 5) + kseg); \
        bf16x8 _r1 = *(const bf16x8*)((S2) + ((arow0 + 16 ) << 9) + (_kt << 5) + kseg); \
        _Pragma("unroll") for (int _n = 0; _n < 4; ++_n) {                    \
            bf16x8 _b = ((const bf16x8*)sB)[(_n << 10) + (_kt << 6) + l];     \
            accD[0][_n] = MFMA16(_d0, _b, accD[0][_n]);                       \
            accD[1][_n] = MFMA16(_d1, _b, accD[1][_n]);                       \
            accR[0][_n] = MFMA16(_r0, _b, accR[0][_n]);                       \
            accR[1][_n] = MFMA16(_r1, _b, accR[1][_n]);                       \
        }                                                                     \
    }                                                                         \
} while (0)

#define ZERO_ACC(acc)                                                         \
    _Pragma("unroll") for (int _m = 0; _m < 2; ++_m)                          \
        _Pragma("unroll") for (int _n = 0; _n < 4; ++_n)                      \
            acc[_m][_n] = (f32x4){0.f, 0.f, 0.f, 0.f}

__global__ __launch_bounds__(256) void k_gemm_mid(
    const short* __restrict__ xb, const short* __restrict__ agg,
    const short* __restrict__ prodD, const short* __restrict__ prodR,
    const short* __restrict__ BpVu, const short* __restrict__ BpEu,
    const float* __restrict__ P,
    short* __restrict__ uvb, short* __restrict__ tvb,
    short* __restrict__ teDb, short* __restrict__ teRb)
{
    __shared__ __align__(16) short sB[64 * 512];   // 64 KB
    int t = threadIdx.x, l = t & 63, w = t >> 6;
    int bid = blockIdx.x;
    int sub = (bid < 256) ? bid : bid - 256;
    int cs = sub & 3, rg = sub >> 2;
    int r0 = rg << 7;                  // 128 rows per block
    int rw = r0 + (w << 5);            // wave's 32 rows
    int cs4 = cs << 2;                 // base nt (16-col tiles)
    int arow0 = rw + (l & 15);
    int kseg = (l >> 4) << 3;

    if (bid < 256) {
        // ---------------- EDGE ----------------
        f32x4 aV[2][4];
        ZERO_ACC(aV);
        STAGE_B(BpEu, 0);              // top half of Weu
        __syncthreads();
        SWEEP1(xb, aV);                // Tv = xb @ Weu_top  (no barriers)
        // write Tv (raw bf16)
        #pragma unroll
        for (int nn = 0; nn < 4; ++nn) {
            int col = (cs << 6) + (nn << 4) + (l & 15);
            #pragma unroll
            for (int mi = 0; mi < 2; ++mi) {
                int rb = rw + (mi << 4) + ((l >> 4) << 2);
                #pragma unroll
                for (int j = 0; j < 4; ++j)
                    tvb[(rb + j) * 256 + col] = f2bf(aV[mi][nn][j]);
            }
        }
        __syncthreads();
        STAGE_B(BpEu, 16);             // bottom half of Weu
        __syncthreads();
        f32x4 aD[2][4], aR[2][4];
        ZERO_ACC(aD);
        ZERO_ACC(aR);
        SWEEP2(prodD, aD, prodR, aR);  // TeD, TeR share B (no barriers)
        #pragma unroll
        for (int nn = 0; nn < 4; ++nn) {
            int col = (cs << 6) + (nn << 4) + (l & 15);
            #pragma unroll
            for (int mi = 0; mi < 2; ++mi) {
                int rb = rw + (mi << 4) + ((l >> 4) << 2);
                #pragma unroll
                for (int j = 0; j < 4; ++j) {
                    teDb[(rb + j) * 256 + col] = f2bf(aD[mi][nn][j]);
                    teRb[(rb + j) * 256 + col] = f2bf(aR[mi][nn][j]);
                }
            }
        }
    } else {
        // ---------------- UV ----------------
        f32x4 acc[2][4];
        ZERO_ACC(acc);
        STAGE_B(BpVu, 0);              // W_vu rows 0..512
        __syncthreads();
        SWEEP1(xb, acc);
        __syncthreads();
        STAGE_B(BpVu, 16);             // W_vu rows 512..1024
        __syncthreads();
        SWEEP1(agg, acc);
        #pragma unroll
        for (int nn = 0; nn < 4; ++nn) {
            int col = (cs << 6) + (nn << 4) + (l & 15);
            float aa = P[8 + col], cc = P[264 + col];
            #pragma unroll
            for (int mi = 0; mi < 2; ++mi) {
                int rb = rw + (mi << 4) + ((l >> 4) << 2);
                #pragma unroll
                for (int j = 0; j < 4; ++j) {
                    float v = fmaxf(fmaf(acc[mi][nn][j], aa, cc), 0.f);
                    uvb[(rb + j) * 256 + col] = f2bf(v);
                }
            }
        }
    }
}

// out = relu(bn5([xb, upd] @ W_fc)), upd computed in-kernel into LDS.
// block: 32 rows x 128 cols (quarter cq), 4 waves (wave 32x32), grid 1024.
// (unchanged from round 7)
#define OUT_COMPUTE(Lb, kc) do {                                              \
    _Pragma("unroll") for (int _kt = 0; _kt < 2; ++_kt) {                     \
        bf16x8 _af[2];                                                        \
        _Pragma("unroll") for (int _mi = 0; _mi < 2; ++_mi) {                 \
            int _row = (_mi << 4) + (l & 15);                                 \
            int _lcolb = (_kt << 6) + ((l >> 4) << 4);                        \
            int _addr = (_row << 6) + ((_lcolb ^ ((_row & 7) << 4)) >> 1);    \
            _af[_mi] = *(const bf16x8*)((Lb) + _addr);                        \
        }                                                                     \
        _Pragma("unroll") for (int _nf = 0; _nf < 2; ++_nf) {                 \
            int _nt = (cq << 3) + (w << 1) + _nf;                             \
            bf16x8 _b = Bp[(_nt * 24 + ((kc) << 1) + _kt) * 64 + l];          \
            _Pragma("unroll") for (int _mi = 0; _mi < 2; ++_mi)               \
                acc[_mi][_nf] = __builtin_amdgcn_mfma_f32_16x16x32_bf16(      \
                    _af[_mi], _b, acc[_mi][_nf], 0, 0, 0);                    \
        }                                                                     \
    }                                                                         \
} while (0)

__global__ __launch_bounds__(256) void k_gemm_out(
    const short* __restrict__ xb,
    const short* __restrict__ tv, const short* __restrict__ teD,
    const short* __restrict__ teR, const short* __restrict__ uv,
    const short* __restrict__ BpFc, const float* __restrict__ P,
    float* __restrict__ out)
{
    __shared__ __align__(16) short sXb[2][32 * 64];   // 8 KB
    __shared__ __align__(16) short updL[4][32 * 64];  // 16 KB
    int t = threadIdx.x, l = t & 63, w = t >> 6;
    int cq = blockIdx.x & 3, rs = blockIdx.x >> 2;
    int r0 = rs << 5;
    const bf16x8* Bp = (const bf16x8*)BpFc;

    int dr = t >> 3, p8 = t & 7;
    int lcs = (p8 ^ (dr & 7)) << 3;
    int xrow = (r0 + dr) << 9;

    // prefetch first two xb chunks before the upd prologue
    bf16x8 gA = *(const bf16x8*)(xb + xrow + lcs);
    bf16x8 gB = *(const bf16x8*)(xb + xrow + 64 + lcs);

    // ---- prologue: upd for rows r0..r0+31, all 256 channels, into LDS ----
    {
        int n = r0 + dr;
        int bh = n >> 6, h = bh & 63, ww = n & 63;
        int bhb = bh & ~63;
        int nUp = ((bhb + ((h + 63) & 63)) << 6) + ww;
        int nLf = (bh << 6) + ((ww + 63) & 63);
        float w0 = P[2060], w1 = P[2061], w2 = P[2062], w3 = P[2063];
        float a4 = P[2], c4 = P[3];
        #pragma unroll
        for (int q = 0; q < 4; ++q) {
            int lc = (q << 6) + lcs;
            bf16x8 vTv = *(const bf16x8*)(tv  + n   * 256 + lc);
            bf16x8 vD  = *(const bf16x8*)(teD + n   * 256 + lc);
            bf16x8 vDu = *(const bf16x8*)(teD + nUp * 256 + lc);
            bf16x8 vR  = *(const bf16x8*)(teR + n   * 256 + lc);
            bf16x8 vRl = *(const bf16x8*)(teR + nLf * 256 + lc);
            bf16x8 vUv = *(const bf16x8*)(uv  + n   * 256 + lc);
            f32x4 a3a = *(const f32x4*)&P[520 + lc], a3b = *(const f32x4*)&P[524 + lc];
            f32x4 c3a = *(const f32x4*)&P[776 + lc], c3b = *(const f32x4*)&P[780 + lc];
            bf16x8 o;
            #pragma unroll
            for (int j = 0; j < 8; ++j) {
                float a3 = (j < 4) ? a3a[j & 3] : a3b[j & 3];
                float c3 = (j < 4) ? c3a[j & 3] : c3b[j & 3];
                float tvv = bf2f(vTv[j]);
                float ueU = fmaxf(fmaf(a3, tvv + bf2f(vDu[j]), c3), 0.f);
                float ueD = fmaxf(fmaf(a3, tvv + bf2f(vD[j]),  c3), 0.f);
                float ueL = fmaxf(fmaf(a3, tvv + bf2f(vRl[j]), c3), 0.f);
                float ueR = fmaxf(fmaf(a3, tvv + bf2f(vR[j]),  c3), 0.f);
                float s = w0 * ueU + w1 * ueD + w2 * ueL + w3 * ueR;
                float ur = fmaxf(fmaf(a4, s, c4), 0.f);
                o[j] = f2bf(ur * bf2f(vUv[j]));
            }
            *(bf16x8*)&updL[q][(dr << 6) + (p8 << 3)] = o;   // swizzled store
        }
    }

    f32x4 acc[2][2];
    #pragma unroll
    for (int mi = 0; mi < 2; ++mi)
        #pragma unroll
        for (int nf = 0; nf < 2; ++nf) acc[mi][nf] = (f32x4){0.f, 0.f, 0.f, 0.f};

    for (int kc2 = 0; kc2 < 8; kc2 += 2) {
        ((bf16x8*)sXb[0])[t] = gA;
        __syncthreads();
        if (kc2 + 2 < 8) gA = *(const bf16x8*)(xb + xrow + ((kc2 + 2) << 6) + lcs);
        OUT_COMPUTE(sXb[0], kc2);
        ((bf16x8*)sXb[1])[t] = gB;
        __syncthreads();
        if (kc2 + 3 < 8) gB = *(const bf16x8*)(xb + xrow + ((kc2 + 3) << 6) + lcs);
        OUT_COMPUTE(sXb[1], kc2 + 1);
    }
    #pragma unroll
    for (int ku = 0; ku < 4; ++ku) OUT_COMPUTE(updL[ku], 8 + ku);

    #pragma unroll
    for (int nf = 0; nf < 2; ++nf) {
        int col = (cq << 7) + (w << 5) + (nf << 4) + (l & 15);
        float a5 = P[1032 + col], c5 = P[1544 + col];
        #pragma unroll
        for (int mi = 0; mi < 2; ++mi) {
            int rbase = r0 + (mi << 4) + ((l >> 4) << 2);
            #pragma unroll
            for (int j = 0; j < 4; ++j) {
                out[(rbase + j) * 512 + col] = fmaxf(fmaf(acc[mi][nf][j], a5, c5), 0.f);
            }
        }
    }
}

extern "C" void kernel_launch(void* const* d_in, const int* in_sizes, int n_in,
                              void* d_out, int out_size, void* d_ws, size_t ws_size,
                              hipStream_t stream)
{
    const float* x    = (const float*)d_in[0];
    const float* w_ea = (const float*)d_in[1];
    const float* b_ea = (const float*)d_in[2];
    const float* g1   = (const float*)d_in[3];
    const float* b1   = (const float*)d_in[4];
    const float* m1   = (const float*)d_in[5];
    const float* v1   = (const float*)d_in[6];
    const float* w_vu = (const float*)d_in[7];
    const float* b_vu = (const float*)d_in[8];
    const float* g2   = (const float*)d_in[9];
    const float* b2   = (const float*)d_in[10];
    const float* m2   = (const float*)d_in[11];
    const float* v2   = (const float*)d_in[12];
    const float* w_eu = (const float*)d_in[13];
    const float* b_eu = (const float*)d_in[14];
    const float* g3   = (const float*)d_in[15];
    const float* b3   = (const float*)d_in[16];
    const float* m3   = (const float*)d_in[17];
    const float* v3   = (const float*)d_in[18];
    const float* w_er = (const float*)d_in[19];
    const float* b_er = (const float*)d_in[20];
    const float* g4   = (const float*)d_in[21];
    const float* b4   = (const float*)d_in[22];
    const float* m4   = (const float*)d_in[23];
    const float* v4   = (const float*)d_in[24];
    const float* w_fc = (const float*)d_in[25];
    const float* g5   = (const float*)d_in[26];
    const float* b5   = (const float*)d_in[27];
    const float* m5   = (const float*)d_in[28];
    const float* v5   = (const float*)d_in[29];

    char* ws = (char*)d_ws;
    float* P = (float*)ws;
    size_t off = 16384;
    short* BpVu = (short*)(ws + off); off += (size_t)1024 * 256 * 2;
    short* BpEu = (short*)(ws + off); off += (size_t)1024 * 256 * 2;
    short* BpFc = (short*)(ws + off); off += (size_t)768 * 512 * 2;
    short* xbb  = (short*)(ws + off); off += (size_t)8192 * 512 * 2;
    short* aggb = (short*)(ws + off); off += (size_t)8192 * 512 * 2;
    short* prodD = (short*)(ws + off); off += (size_t)8192 * 512 * 2;
    short* prodR = (short*)(ws + off); off += (size_t)8192 * 512 * 2;
    short* uvb  = (short*)(ws + off); off += (size_t)8192 * 256 * 2;
    short* tvb  = (short*)(ws + off); off += (size_t)8192 * 256 * 2;
    short* teDb = (short*)(ws + off); off += (size_t)8192 * 256 * 2;
    short* teRb = (short*)(ws + off); off += (size_t)8192 * 256 * 2;

    k_front<<<2497, 256, 0, stream>>>(x, w_ea, b_ea, g1, b1, m1, v1,
                                      w_vu, w_eu, w_fc,
                                      b_vu, g2, b2, m2, v2,
                                      b_eu, g3, b3, m3, v3,
                                      w_er, b_er, g4, b4, m4, v4,
                                      g5, b5, m5, v5,
                                      xbb, aggb, prodD, prodR,
                                      BpVu, BpEu, BpFc, P);
    k_gemm_mid<<<512, 256, 0, stream>>>(xbb, aggb, prodD, prodR,
                                        BpVu, BpEu, P,
                                        uvb, tvb, teDb, teRb);
    k_gemm_out<<<1024, 256, 0, stream>>>(xbb, tvb, teDb, teRb, uvb, BpFc, P,
                                         (float*)d_out);
}